// Round 12
// baseline (106.134 us; speedup 1.0000x reference)
//
#include <hip/hip_runtime.h>
#include <cstdint>
#include <math.h>

#pragma clang fp contract(off)

typedef unsigned int u32;
typedef unsigned long long u64;

#define HFEAT 512
#define WFEAT 512
#define NPIX (HFEAT*WFEAT)          // 262144
#define NANCH (NPIX*9)              // 2359296
#define TOPK 4000
#define IMG_SZ 16384.0f
#define NBUCKET 8192
#define CAP 32768
#define NWORD 63                    // ceil(TOPK/64)
#define RCACHE 224                  // suppressor-row LDS cache slots
#define COARSE_CUT (-3.5f)
#define COARSE_BUK_SAFE 1537        // thr must be >= this so -1 margin stays inside coarse

// ---- workspace layout (bytes) ----
#define WS_META 32768                // u32[16]  [0]=M [1]=thr [3]=coarseN [5]=fast
#define WS_SUP  32832                // u64[64]
#define WS_CKEY 33856                // u64[CAP] 262144 -> 296000 (packed s1|~idx)
#define WS_NX1  312000               // f32[TOPK] each
#define WS_NY1  328000
#define WS_NX2  344000
#define WS_NY2  360000
#define WS_NAR  376000
#define WS_VAL  392000               // u32[TOPK] -> 408000
#define WS_MASK 408000               // u64[TOPK*64] = 2048000 -> 2456000
#define WS_RANK WS_MASK              // u32[4*CAP]=524288 alias (consumed before k_mask)
#define WS_COARSE (WS_MASK + 524288) // u64[CAP]=262144 alias (consumed before k_mask)
#define WS_DIAG 2456000              // u64[TOPK] -> 2488000

// d-bucket: larger bucket == more negative d == higher score (d <= -2 domain)
__device__ __forceinline__ int dbucket_bits(u32 bits) {
    int b = (int)((bits - 0xC0000000u) >> 12);
    return (b > (NBUCKET - 1)) ? (NBUCKET - 1) : b;
}

// exact f32 s1 for l1>l0, bit-identical to numpy softmax chain
__device__ __forceinline__ float score1(float d) {
    float e0 = (float)::exp((double)d);
    float den = e0 + 1.0f;
    return 1.0f / den;
}

// full softmax (both outputs), identical op order to ref
__device__ __forceinline__ void softmax2(float l0, float l1, float& s0, float& s1) {
    float m = fmaxf(l0, l1);
    float a0 = l0 - m;
    float a1 = l1 - m;
    float e0 = (float)::exp((double)a0);
    float e1 = (float)::exp((double)a1);
    float den = e0 + e1;
    s0 = e0 / den;
    s1 = e1 / den;
}

// zero meta (16 u32) + supany (128 u32)
__global__ void k_zero(u32* ws32) {
    int t = threadIdx.x;
    if (t < 144) ws32[WS_META/4 + t] = 0;
}

// stream obj as float4 (2 anchors/load); stage d < -3.5 per-block; 1 atomic/block
__global__ void k_coarse(const float4* __restrict__ o4, u64* __restrict__ coarse,
                         u32* __restrict__ meta) {
    __shared__ u64 stage[512];
    __shared__ u32 scnt, sbase;
    int tid = threadIdx.x;
    if (tid == 0) scnt = 0;
    __syncthreads();
    int base = blockIdx.x * 2304;          // float4 index; 4608 anchors per block
#pragma unroll
    for (int k = 0; k < 9; ++k) {
        int a4 = base + k * 256 + tid;
        float4 v = o4[a4];
        float d0 = v.x - v.y;
        float d1 = v.z - v.w;
        if (d0 < COARSE_CUT) {
            u32 p = atomicAdd(&scnt, 1u);
            if (p < 512) stage[p] = ((u64)__float_as_uint(d0) << 32) | (u32)(2*a4);
        }
        if (d1 < COARSE_CUT) {
            u32 p = atomicAdd(&scnt, 1u);
            if (p < 512) stage[p] = ((u64)__float_as_uint(d1) << 32) | (u32)(2*a4 + 1);
        }
    }
    __syncthreads();
    u32 cntr = scnt;
    u32 cnt = (cntr > 512u) ? 512u : cntr;
    if (tid == 0 && cntr) {
        // overflow guard: inflate coarseN past CAP -> fallback path
        sbase = atomicAdd(&meta[3], (cntr > 512u) ? (u32)CAP : cnt);
    }
    __syncthreads();
    if (cnt)
        for (u32 t = tid; t < cnt; t += 256) {
            u32 pos = sbase + t;
            if (pos < CAP) coarse[pos] = stage[t];
        }
}

// single block: histogram coarse -> threshold (-1 tie margin) -> filter+compact ckeyp.
// Zero global atomics on the fast path. Fallback: slow 1-block full scan (never taken).
__global__ __launch_bounds__(1024) void k_selectkey(const float* __restrict__ obj,
                                                    u32* __restrict__ meta,
                                                    const u64* __restrict__ coarse,
                                                    u64* __restrict__ ckeyp) {
    __shared__ u32 lh[NBUCKET];   // 32 KB
    __shared__ u32 ss[1024];
    __shared__ u32 ps[1024];
    __shared__ u32 thr_s;
    int tid = threadIdx.x;
    for (int b = tid; b < NBUCKET; b += 1024) lh[b] = 0;
    if (tid == 0) thr_s = 0;
    __syncthreads();
    u32 coarseN = meta[3];
    bool ok = (coarseN >= (u32)TOPK) && (coarseN < (u32)CAP);
    if (ok) {
        for (u32 t = tid; t < coarseN; t += 1024)
            atomicAdd(&lh[dbucket_bits((u32)(coarse[t] >> 32))], 1u);
    }
    __syncthreads();
    u32 local = 0;
#pragma unroll
    for (int j = 0; j < 8; ++j) local += lh[tid*8 + j];
    ss[tid] = local;
    __syncthreads();
    for (int off = 1; off < 1024; off <<= 1) {       // suffix scan
        u32 v = (tid + off < 1024) ? ss[tid + off] : 0;
        __syncthreads();
        ss[tid] += v;
        __syncthreads();
    }
    if (ok) {
        u32 S_t = ss[tid];
        u32 S_next = (tid < 1023) ? ss[tid+1] : 0;
        if (S_t >= TOPK && S_next < TOPK) {
            u32 cum = S_next;
            int bsel = tid*8;
            for (int b = tid*8 + 7; b >= tid*8; --b) {
                cum += lh[b];
                if (cum >= TOPK) { bsel = b; break; }
            }
            thr_s = (u32)((bsel > 0) ? bsel - 1 : 0);
        }
    }
    __syncthreads();
    bool fast = ok && (thr_s >= (u32)COARSE_BUK_SAFE);
    if (fast) {
        int thr = (int)thr_s;
        u32 mycnt = 0;
        for (u32 t = tid; t < coarseN; t += 1024)
            if (dbucket_bits((u32)(coarse[t] >> 32)) >= thr) mycnt++;
        ps[tid] = mycnt;
        __syncthreads();
        for (int off = 1; off < 1024; off <<= 1) {   // inclusive prefix scan
            u32 v = (tid >= off) ? ps[tid - off] : 0;
            __syncthreads();
            ps[tid] += v;
            __syncthreads();
        }
        u32 w = ps[tid] - mycnt;
        for (u32 t = tid; t < coarseN; t += 1024) {
            u64 e = coarse[t];
            u32 dbits = (u32)(e >> 32);
            if (dbucket_bits(dbits) >= thr) {
                float s1 = score1(__uint_as_float(dbits));
                ckeyp[w++] = ((u64)__float_as_uint(s1) << 32) |
                             (u32)(~(u32)(e & 0xFFFFFFFFull));
            }
        }
        if (tid == 0) { meta[0] = ps[1023]; meta[1] = thr_s; meta[5] = 1u; }
    } else {
        // correctness fallback (never taken for this input): slow 1-block scan
        const float2* o2 = (const float2*)obj;
        for (int a = tid; a < NANCH; a += 1024) {
            float2 v = o2[a];
            float d = v.x - v.y;
            if (d < 0.0f) {
                float s1 = score1(d);
                if (s1 > 0.5f) {
                    u32 pos = atomicAdd(&meta[0], 1u);
                    if (pos < CAP)
                        ckeyp[pos] = ((u64)__float_as_uint(s1) << 32) | (u32)(~(u32)a);
                }
            }
        }
        if (tid == 0) meta[5] = 0u;
    }
}

#define RSL 1024
#define NSLICE 4
// partial rank, atomic-free: block (bx,by) counts candidates against ref slice bx
__global__ void k_rank(const u32* __restrict__ meta, const u64* __restrict__ ckeyp,
                       u32* __restrict__ rankbuf) {
    __shared__ u64 lk[RSL];
    int tid = threadIdx.x;
    u32 Mu = meta[0];
    int M = (int)(Mu < (u32)CAP ? Mu : (u32)CAP);
    int c = blockIdx.y * 256 + tid;
    if (blockIdx.y * 256 >= M) return;
    bool act = (c < M);
    u64 mypk = act ? ckeyp[c] : 0ull;
    int cnt = 0;
    for (int t0 = blockIdx.x * RSL; t0 < M; t0 += NSLICE * RSL) {
        __syncthreads();
        for (int j = tid; j < RSL; j += 256)
            lk[j] = (t0 + j < M) ? ckeyp[t0 + j] : 0ull;
        __syncthreads();
#pragma unroll 16
        for (int j = 0; j < RSL; ++j)
            cnt += (lk[j] > mypk) ? 1 : 0;
    }
    rankbuf[blockIdx.x * CAP + c] = (u32)cnt;
}

// rank = sum of slice partials; gather + decode + write output row r directly
__global__ void k_selgather(const u32* __restrict__ meta, const u64* __restrict__ ckeyp,
                            const u32* __restrict__ rankbuf,
                            const float* __restrict__ obj, const float* __restrict__ reg,
                            const float* __restrict__ anch, float* __restrict__ out,
                            float* __restrict__ nx1, float* __restrict__ ny1,
                            float* __restrict__ nx2, float* __restrict__ ny2,
                            float* __restrict__ nar, u32* __restrict__ valid) {
    u32 Mu = meta[0];
    int M = (int)(Mu < (u32)CAP ? Mu : (u32)CAP);
    int c = blockIdx.x * 256 + threadIdx.x;
    if (c >= M) return;
    u32 r = rankbuf[c] + rankbuf[CAP + c] + rankbuf[2*CAP + c] + rankbuf[3*CAP + c];
    if (r >= TOPK) return;
    u32 i = ~(u32)(ckeyp[c] & 0xFFFFFFFFull);
    u32 p = i / 9u, k = i - p * 9u;
    float l0 = obj[(size_t)p*18 + 2*k];
    float l1 = obj[(size_t)p*18 + 2*k + 1];
    float s0, s1;
    softmax2(l0, l1, s0, s1);
    const float* rg = reg + (size_t)p*36 + 4*k;
    float t0 = rg[0], t1 = rg[1], t2 = rg[2], t3 = rg[3];
    const float* an = anch + (size_t)i*4;
    float a0 = an[0], a1 = an[1], a2 = an[2], a3 = an[3];
    float cx = a0 + a2/2.0f + t0*a2;
    float cy = a1 + a3/2.0f + t1*a3;
    float w = a2 * (float)::exp((double)t2);
    float h = a3 * (float)::exp((double)t3);
    float bx = cx - w/2.0f;
    float by = cy - h/2.0f;
    float x1 = fminf(fmaxf(bx, 0.0f), IMG_SZ);
    float y1 = fminf(fmaxf(by, 0.0f), IMG_SZ);
    float x2 = fminf(fmaxf(bx + w, 0.0f), IMG_SZ);
    float y2 = fminf(fmaxf(by + h, 0.0f), IMG_SZ);
    float bw = x2 - x1, bh = y2 - y1;
    out[4*r+0] = x1;
    out[4*r+1] = y1;
    out[4*r+2] = bw;
    out[4*r+3] = bh;
    out[16000 + 2*r]     = s0;
    out[16000 + 2*r + 1] = s1;
    nx1[r] = x1; ny1[r] = y1;
    nx2[r] = x1 + bw;
    ny2[r] = y1 + bh;
    nar[r] = bw * bh;
    valid[r] = (s1 > 0.5f) ? 1u : 0u;
}

__device__ __forceinline__ bool iou_gt(float x1a, float y1a, float x2a, float y2a, float aA,
                                       float x1b, float y1b, float x2b, float y2b, float aB) {
    float iw = fminf(x2a, x2b) - fmaxf(x1a, x1b);
    float ih = fminf(y2a, y2b) - fmaxf(y1a, y1b);
    iw = fmaxf(iw, 0.0f);
    ih = fmaxf(ih, 0.0f);
    float inter = iw * ih;
    float iou = inter / (aA + aB - inter + 1e-8f);
    return iou > 0.3f;
}

// full suppression bitmask + per-row summary + diagonal word; zero-row early-exit
__global__ void k_mask(const float* __restrict__ nx1, const float* __restrict__ ny1,
                       const float* __restrict__ nx2, const float* __restrict__ ny2,
                       const float* __restrict__ nar, u64* __restrict__ mask,
                       u64* __restrict__ diag, u64* __restrict__ supany) {
    __shared__ float cx1[64], cy1[64], cx2[64], cy2[64], car[64];
    int w = blockIdx.y;
    int j0 = w * 64;
    int tid = threadIdx.x;
    int i = blockIdx.x * 256 + tid;
    if (j0 + 63 < (int)(blockIdx.x * 256)) {
        if (i < TOPK) mask[(size_t)i * 64 + w] = 0ull;
        return;
    }
    if (tid < 64) {
        int j = j0 + tid;
        bool v = j < TOPK;
        cx1[tid] = v ? nx1[j] : 1e9f;
        cy1[tid] = v ? ny1[j] : 1e9f;
        cx2[tid] = v ? nx2[j] : 1e9f;
        cy2[tid] = v ? ny2[j] : 1e9f;
        car[tid] = v ? nar[j] : 0.f;
    }
    __syncthreads();
    if (i >= TOPK) return;
    float x1 = nx1[i], y1 = ny1[i], x2 = nx2[i], y2 = ny2[i], ar = nar[i];
    u64 bits = 0;
#pragma unroll
    for (int b = 0; b < 64; ++b) {
        int j = j0 + b;
        if (j < TOPK && j > i &&
            iou_gt(x1, y1, x2, y2, ar, cx1[b], cy1[b], cx2[b], cy2[b], car[b]))
            bits |= (1ull << b);
    }
    mask[(size_t)i * 64 + w] = bits;
    if (w == (i >> 6)) diag[i] = bits;
    u64 anyb = __ballot(bits != 0ull);
    if ((tid & 63) == 0 && anyb) atomicOr(&supany[i >> 6], anyb);
}

// 512 threads: build valm from valid via ballots; preload suppressor rows + diag; wave 0 scans
__global__ __launch_bounds__(512) void k_scan_nms(const u64* __restrict__ mask,
                                                  const u64* __restrict__ diag,
                                                  const u64* __restrict__ supany,
                                                  const u32* __restrict__ valid,
                                                  float* __restrict__ out) {
    __shared__ u64 dlds[NWORD * 64];
    __shared__ u64 cache[RCACHE * 64];
    __shared__ u32 rowlist[RCACHE];
    __shared__ u32 nrows_s;
    __shared__ u64 vml[64];
    __shared__ u64 keep_s[64];
    int tid = threadIdx.x;
    int wave = tid >> 6, lane = tid & 63;

    // valm from valid: 8 waves cover 64 groups
    for (int g = wave; g < 64; g += 8) {
        int t = g * 64 + lane;
        u32 v = (t < TOPK) ? valid[t] : 0u;
        u64 bm = __ballot(v != 0u);
        if (lane == 0) vml[g] = bm;
    }
    for (int t = tid; t < NWORD * 64; t += 512)
        dlds[t] = (t < TOPK) ? diag[t] : 0ull;

    int excl = 0;
    u64 sa = 0;
    if (wave == 0) {
        sa = supany[lane];
        int c = (int)__popcll(sa);
        int pfx = c;
        for (int off = 1; off < 64; off <<= 1) {
            int n = __shfl_up(pfx, off);
            if (lane >= off) pfx += n;
        }
        excl = pfx - c;
        int total = __shfl(pfx, 63);
        if (lane == 0) nrows_s = (u32)((total < RCACHE) ? total : RCACHE);
        int s = excl; u64 t = sa;
        while (t) {
            int b = (int)__builtin_ctzll(t); t &= t - 1;
            if (s < RCACHE) rowlist[s] = (u32)((lane << 6) | b);
            s++;
        }
    }
    __syncthreads();
    int R = (int)nrows_s;
    {
        const int TW = RCACHE * 64;
        for (int t0 = tid; t0 < TW; t0 += 512 * 8) {
            u64 v[8];
#pragma unroll
            for (int u = 0; u < 8; ++u) {
                int t = t0 + u * 512;
                int sl = t >> 6;
                int row = (t < TW && sl < R) ? (int)rowlist[sl] : 0;
                v[u] = (t < TW) ? mask[(size_t)row * 64 + (t & 63)] : 0ull;
            }
#pragma unroll
            for (int u = 0; u < 8; ++u) {
                int t = t0 + u * 512;
                if (t < TW) cache[t] = v[u];
            }
        }
    }
    __syncthreads();
    if (wave == 0) {
        u64 kw = vml[lane];
        u64 gm = __ballot((sa & kw) != 0ull);
        while (gm) {
            int g = (int)__builtin_ctzll(gm); gm &= gm - 1;
            u64 wg  = __shfl(kw, g);
            u64 sag = __shfl(sa, g);
            u64 supAlive = wg & sag;
            if (supAlive == 0ull) continue;
            int sbase = __shfl(excl, g);
            u64 dg = dlds[(g << 6) | lane];
            u64 am = wg, act = supAlive, keptSup = 0ull;
            while (act) {
                int s = (int)__builtin_ctzll(act);
                u64 sup = __shfl(dg, s);
                am &= ~sup;
                keptSup |= (1ull << s);
                act &= ~(1ull << s);
                act &= am;
            }
            u64 acc = 0, t = keptSup;
            while (t) {
                int s1b = (int)__builtin_ctzll(t); t &= t - 1;
                int sl1 = sbase + (int)__popcll(sag & ((1ull << s1b) - 1ull));
                if (t) {
                    int s2b = (int)__builtin_ctzll(t); t &= t - 1;
                    int sl2 = sbase + (int)__popcll(sag & ((1ull << s2b) - 1ull));
                    u64 ra = (sl1 < RCACHE) ? cache[(sl1 << 6) | lane]
                                            : mask[(size_t)((g << 6) | s1b) * 64 + lane];
                    u64 rb = (sl2 < RCACHE) ? cache[(sl2 << 6) | lane]
                                            : mask[(size_t)((g << 6) | s2b) * 64 + lane];
                    acc |= ra | rb;
                } else {
                    acc |= (sl1 < RCACHE) ? cache[(sl1 << 6) | lane]
                                          : mask[(size_t)((g << 6) | s1b) * 64 + lane];
                }
            }
            kw &= ~acc;
        }
        keep_s[lane] = kw;
    }
    __syncthreads();
    for (int t = tid; t < TOPK; t += 512)
        out[24000 + t] = ((keep_s[t >> 6] >> (t & 63)) & 1ull) ? 1.0f : 0.0f;
}

extern "C" void kernel_launch(void* const* d_in, const int* in_sizes, int n_in,
                              void* d_out, int out_size, void* d_ws, size_t ws_size,
                              hipStream_t stream) {
    const float* obj  = (const float*)d_in[0];
    const float* reg  = (const float*)d_in[1];
    const float* anch = (const float*)d_in[2];
    float* out = (float*)d_out;
    char* ws = (char*)d_ws;

    u32* meta = (u32*)(ws + WS_META);
    u64* supany = (u64*)(ws + WS_SUP);
    u64* ckeyp = (u64*)(ws + WS_CKEY);
    float* nx1 = (float*)(ws + WS_NX1);
    float* ny1 = (float*)(ws + WS_NY1);
    float* nx2 = (float*)(ws + WS_NX2);
    float* ny2 = (float*)(ws + WS_NY2);
    float* nar = (float*)(ws + WS_NAR);
    u32* valid = (u32*)(ws + WS_VAL);
    u64* mask  = (u64*)(ws + WS_MASK);
    u64* diag  = (u64*)(ws + WS_DIAG);
    u32* rankbuf = (u32*)(ws + WS_RANK);
    u64* coarse  = (u64*)(ws + WS_COARSE);

    hipLaunchKernelGGL(k_zero, dim3(1), dim3(256), 0, stream, (u32*)ws);
    hipLaunchKernelGGL(k_coarse, dim3(NANCH / 4608), dim3(256), 0, stream,
                       (const float4*)obj, coarse, meta);
    hipLaunchKernelGGL(k_selectkey, dim3(1), dim3(1024), 0, stream, obj, meta, coarse, ckeyp);
    hipLaunchKernelGGL(k_rank, dim3(NSLICE, CAP/256), dim3(256), 0, stream, meta, ckeyp, rankbuf);
    hipLaunchKernelGGL(k_selgather, dim3(CAP/256), dim3(256), 0, stream,
                       meta, ckeyp, rankbuf, obj, reg, anch, out,
                       nx1, ny1, nx2, ny2, nar, valid);
    hipLaunchKernelGGL(k_mask, dim3((TOPK + 255) / 256, 64), dim3(256), 0, stream,
                       nx1, ny1, nx2, ny2, nar, mask, diag, supany);
    hipLaunchKernelGGL(k_scan_nms, dim3(1), dim3(512), 0, stream, mask, diag, supany, valid, out);
}

// Round 13
// 97.784 us; speedup vs baseline: 1.0854x; 1.0854x over previous
//
#include <hip/hip_runtime.h>
#include <cstdint>
#include <math.h>

#pragma clang fp contract(off)

typedef unsigned int u32;
typedef unsigned long long u64;

#define HFEAT 512
#define WFEAT 512
#define NPIX (HFEAT*WFEAT)          // 262144
#define NANCH (NPIX*9)              // 2359296
#define TOPK 4000
#define IMG_SZ 16384.0f
#define NBUCKET 8192
#define CAP 32768
#define NWORD 63                    // ceil(TOPK/64)
#define RCACHE 224                  // suppressor-row LDS cache slots
#define COARSE_CUT (-3.5f)
#define COARSE_BUK_SAFE 1537        // thr must be >= this so -1 margin stays inside coarse

// ---- workspace layout (bytes) ----
#define WS_META 32768                // u32[16]  [0]=M [1]=thr [3]=coarseN [5]=fast
#define WS_SUP  32832                // u64[64]
#define WS_CKEY 33856                // u64[CAP] 262144 -> 296000 (packed s1|~idx)
#define WS_NX1  312000               // f32[TOPK] each
#define WS_NY1  328000
#define WS_NX2  344000
#define WS_NY2  360000
#define WS_NAR  376000
#define WS_VAL  392000               // u32[TOPK] -> 408000
#define WS_MASK 408000               // u64[TOPK*64] = 2048000 -> 2456000
#define WS_RANK WS_MASK              // u32[4*CAP]=524288 alias (consumed before k_mask)
#define WS_COARSE (WS_MASK + 524288) // u64[CAP]=262144 alias (consumed before k_mask)
#define WS_DIAG 2456000              // u64[TOPK] -> 2488000

// d-bucket: larger bucket == more negative d == higher score (d <= -2 domain)
__device__ __forceinline__ int dbucket_bits(u32 bits) {
    int b = (int)((bits - 0xC0000000u) >> 12);
    return (b > (NBUCKET - 1)) ? (NBUCKET - 1) : b;
}

// exact f32 s1 for l1>l0, bit-identical to numpy softmax chain
__device__ __forceinline__ float score1(float d) {
    float e0 = (float)::exp((double)d);
    float den = e0 + 1.0f;
    return 1.0f / den;
}

// full softmax (both outputs), identical op order to ref
__device__ __forceinline__ void softmax2(float l0, float l1, float& s0, float& s1) {
    float m = fmaxf(l0, l1);
    float a0 = l0 - m;
    float a1 = l1 - m;
    float e0 = (float)::exp((double)a0);
    float e1 = (float)::exp((double)a1);
    float den = e0 + e1;
    s0 = e0 / den;
    s1 = e1 / den;
}

// zero meta (16 u32) + supany (128 u32)
__global__ void k_zero(u32* ws32) {
    int t = threadIdx.x;
    if (t < 144) ws32[WS_META/4 + t] = 0;
}

// stream obj as float4 (2 anchors/load); stage d < -3.5 per-block; 1 atomic/block
__global__ void k_coarse(const float4* __restrict__ o4, u64* __restrict__ coarse,
                         u32* __restrict__ meta) {
    __shared__ u64 stage[512];
    __shared__ u32 scnt, sbase;
    int tid = threadIdx.x;
    if (tid == 0) scnt = 0;
    __syncthreads();
    int base = blockIdx.x * 2304;          // float4 index; 4608 anchors per block
#pragma unroll
    for (int k = 0; k < 9; ++k) {
        int a4 = base + k * 256 + tid;
        float4 v = o4[a4];
        float d0 = v.x - v.y;
        float d1 = v.z - v.w;
        if (d0 < COARSE_CUT) {
            u32 p = atomicAdd(&scnt, 1u);
            if (p < 512) stage[p] = ((u64)__float_as_uint(d0) << 32) | (u32)(2*a4);
        }
        if (d1 < COARSE_CUT) {
            u32 p = atomicAdd(&scnt, 1u);
            if (p < 512) stage[p] = ((u64)__float_as_uint(d1) << 32) | (u32)(2*a4 + 1);
        }
    }
    __syncthreads();
    u32 cntr = scnt;
    u32 cnt = (cntr > 512u) ? 512u : cntr;
    if (tid == 0 && cntr) {
        // overflow guard: inflate coarseN past CAP -> fallback path
        sbase = atomicAdd(&meta[3], (cntr > 512u) ? (u32)CAP : cnt);
    }
    __syncthreads();
    if (cnt)
        for (u32 t = tid; t < cnt; t += 256) {
            u32 pos = sbase + t;
            if (pos < CAP) coarse[pos] = stage[t];
        }
}

// single block: LDS histogram over coarse d-buckets -> threshold (with -1 tie margin)
__global__ __launch_bounds__(1024) void k_select(const u64* __restrict__ coarse,
                                                 u32* __restrict__ meta) {
    __shared__ u32 lh[NBUCKET];
    __shared__ u32 ss[1024];
    int tid = threadIdx.x;
    for (int b = tid; b < NBUCKET; b += 1024) lh[b] = 0;
    __syncthreads();
    u32 coarseN = meta[3];
    bool ok = (coarseN >= (u32)TOPK) && (coarseN < (u32)CAP);
    if (ok) {
        for (u32 t = tid; t < coarseN; t += 1024)
            atomicAdd(&lh[dbucket_bits((u32)(coarse[t] >> 32))], 1u);
    }
    __syncthreads();
    u32 local = 0;
#pragma unroll
    for (int j = 0; j < 8; ++j) local += lh[tid*8 + j];
    ss[tid] = local;
    __syncthreads();
    for (int off = 1; off < 1024; off <<= 1) {
        u32 v = (tid + off < 1024) ? ss[tid + off] : 0;
        __syncthreads();
        ss[tid] += v;
        __syncthreads();
    }
    if (!ok) { if (tid == 0) { meta[1] = 0; meta[5] = 0; } return; }
    u32 S_t = ss[tid];
    u32 S_next = (tid < 1023) ? ss[tid+1] : 0;
    if (S_t >= TOPK && S_next < TOPK) {
        u32 cum = S_next;
        int bsel = tid*8;
        for (int b = tid*8 + 7; b >= tid*8; --b) {
            cum += lh[b];
            if (cum >= TOPK) { bsel = b; break; }
        }
        u32 thr = (u32)((bsel > 0) ? bsel - 1 : 0);
        meta[1] = thr;
        meta[5] = (thr >= COARSE_BUK_SAFE) ? 1u : 0u;   // margin inside coarse region
    }
}

// filter coarse by bucket>=thr, compact to ckeyp (one atomic per block).
// Fallback (!fast): CAP-capped full rescan (never taken for this input).
__global__ void k_key(const float* __restrict__ obj, u32* __restrict__ meta,
                      const u64* __restrict__ coarse, u64* __restrict__ ckeyp) {
    __shared__ u64 stage[256];
    __shared__ u32 scnt, sbase;
    int tid = threadIdx.x;
    if (tid == 0) scnt = 0;
    __syncthreads();
    bool fast = meta[5] != 0u;
    if (fast) {
        u32 coarseN = meta[3];
        int thr = (int)meta[1];
        u32 t = blockIdx.x * 256 + tid;
        if (blockIdx.x * 256 < coarseN) {
            if (t < coarseN) {
                u64 e = coarse[t];
                u32 dbits = (u32)(e >> 32);
                if (dbucket_bits(dbits) >= thr) {
                    float s1 = score1(__uint_as_float(dbits));
                    u32 bits = __float_as_uint(s1);
                    u32 p = atomicAdd(&scnt, 1u);
                    stage[p] = ((u64)bits << 32) | (u32)(~(u32)(e & 0xFFFFFFFFull));
                }
            }
            __syncthreads();
            u32 cnt = scnt;
            if (tid == 0 && cnt) sbase = atomicAdd(&meta[0], cnt);
            __syncthreads();
            if (cnt && tid < cnt) {
                u32 pos = sbase + tid;
                if (pos < CAP) ckeyp[pos] = stage[tid];
            }
        }
    } else {
        const float2* o2 = (const float2*)obj;
        for (int a = blockIdx.x * 256 + tid; a < NANCH; a += gridDim.x * 256) {
            float2 v = o2[a];
            float d = v.x - v.y;
            if (d < 0.0f) {
                float s1 = score1(d);
                if (s1 > 0.5f) {
                    u32 bits = __float_as_uint(s1);
                    u32 pos = atomicAdd(&meta[0], 1u);
                    if (pos < CAP) ckeyp[pos] = ((u64)bits << 32) | (u32)(~(u32)a);
                }
            }
        }
    }
}

#define RSL 1024
#define NSLICE 4
// partial rank, atomic-free: block (bx,by) counts candidates against ref slice bx
__global__ void k_rank(const u32* __restrict__ meta, const u64* __restrict__ ckeyp,
                       u32* __restrict__ rankbuf) {
    __shared__ u64 lk[RSL];
    int tid = threadIdx.x;
    u32 Mu = meta[0];
    int M = (int)(Mu < (u32)CAP ? Mu : (u32)CAP);
    int c = blockIdx.y * 256 + tid;
    if (blockIdx.y * 256 >= M) return;
    bool act = (c < M);
    u64 mypk = act ? ckeyp[c] : 0ull;
    int cnt = 0;
    for (int t0 = blockIdx.x * RSL; t0 < M; t0 += NSLICE * RSL) {
        __syncthreads();
        for (int j = tid; j < RSL; j += 256)
            lk[j] = (t0 + j < M) ? ckeyp[t0 + j] : 0ull;
        __syncthreads();
#pragma unroll 16
        for (int j = 0; j < RSL; ++j)
            cnt += (lk[j] > mypk) ? 1 : 0;
    }
    rankbuf[blockIdx.x * CAP + c] = (u32)cnt;
}

// rank = sum of slice partials; gather + decode + write output row r directly
__global__ void k_selgather(const u32* __restrict__ meta, const u64* __restrict__ ckeyp,
                            const u32* __restrict__ rankbuf,
                            const float* __restrict__ obj, const float* __restrict__ reg,
                            const float* __restrict__ anch, float* __restrict__ out,
                            float* __restrict__ nx1, float* __restrict__ ny1,
                            float* __restrict__ nx2, float* __restrict__ ny2,
                            float* __restrict__ nar, u32* __restrict__ valid) {
    u32 Mu = meta[0];
    int M = (int)(Mu < (u32)CAP ? Mu : (u32)CAP);
    int c = blockIdx.x * 256 + threadIdx.x;
    if (c >= M) return;
    u32 r = rankbuf[c] + rankbuf[CAP + c] + rankbuf[2*CAP + c] + rankbuf[3*CAP + c];
    if (r >= TOPK) return;
    u32 i = ~(u32)(ckeyp[c] & 0xFFFFFFFFull);
    u32 p = i / 9u, k = i - p * 9u;
    float l0 = obj[(size_t)p*18 + 2*k];
    float l1 = obj[(size_t)p*18 + 2*k + 1];
    float s0, s1;
    softmax2(l0, l1, s0, s1);
    const float* rg = reg + (size_t)p*36 + 4*k;
    float t0 = rg[0], t1 = rg[1], t2 = rg[2], t3 = rg[3];
    const float* an = anch + (size_t)i*4;
    float a0 = an[0], a1 = an[1], a2 = an[2], a3 = an[3];
    float cx = a0 + a2/2.0f + t0*a2;
    float cy = a1 + a3/2.0f + t1*a3;
    float w = a2 * (float)::exp((double)t2);
    float h = a3 * (float)::exp((double)t3);
    float bx = cx - w/2.0f;
    float by = cy - h/2.0f;
    float x1 = fminf(fmaxf(bx, 0.0f), IMG_SZ);
    float y1 = fminf(fmaxf(by, 0.0f), IMG_SZ);
    float x2 = fminf(fmaxf(bx + w, 0.0f), IMG_SZ);
    float y2 = fminf(fmaxf(by + h, 0.0f), IMG_SZ);
    float bw = x2 - x1, bh = y2 - y1;
    out[4*r+0] = x1;
    out[4*r+1] = y1;
    out[4*r+2] = bw;
    out[4*r+3] = bh;
    out[16000 + 2*r]     = s0;
    out[16000 + 2*r + 1] = s1;
    nx1[r] = x1; ny1[r] = y1;
    nx2[r] = x1 + bw;
    ny2[r] = y1 + bh;
    nar[r] = bw * bh;
    valid[r] = (s1 > 0.5f) ? 1u : 0u;
}

__device__ __forceinline__ bool iou_gt(float x1a, float y1a, float x2a, float y2a, float aA,
                                       float x1b, float y1b, float x2b, float y2b, float aB) {
    float iw = fminf(x2a, x2b) - fmaxf(x1a, x1b);
    float ih = fminf(y2a, y2b) - fmaxf(y1a, y1b);
    iw = fmaxf(iw, 0.0f);
    ih = fmaxf(ih, 0.0f);
    float inter = iw * ih;
    float iou = inter / (aA + aB - inter + 1e-8f);
    return iou > 0.3f;
}

// full suppression bitmask + per-row summary + diagonal word; zero-row early-exit
__global__ void k_mask(const float* __restrict__ nx1, const float* __restrict__ ny1,
                       const float* __restrict__ nx2, const float* __restrict__ ny2,
                       const float* __restrict__ nar, u64* __restrict__ mask,
                       u64* __restrict__ diag, u64* __restrict__ supany) {
    __shared__ float cx1[64], cy1[64], cx2[64], cy2[64], car[64];
    int w = blockIdx.y;
    int j0 = w * 64;
    int tid = threadIdx.x;
    int i = blockIdx.x * 256 + tid;
    if (j0 + 63 < (int)(blockIdx.x * 256)) {
        if (i < TOPK) mask[(size_t)i * 64 + w] = 0ull;
        return;
    }
    if (tid < 64) {
        int j = j0 + tid;
        bool v = j < TOPK;
        cx1[tid] = v ? nx1[j] : 1e9f;
        cy1[tid] = v ? ny1[j] : 1e9f;
        cx2[tid] = v ? nx2[j] : 1e9f;
        cy2[tid] = v ? ny2[j] : 1e9f;
        car[tid] = v ? nar[j] : 0.f;
    }
    __syncthreads();
    if (i >= TOPK) return;
    float x1 = nx1[i], y1 = ny1[i], x2 = nx2[i], y2 = ny2[i], ar = nar[i];
    u64 bits = 0;
#pragma unroll
    for (int b = 0; b < 64; ++b) {
        int j = j0 + b;
        if (j < TOPK && j > i &&
            iou_gt(x1, y1, x2, y2, ar, cx1[b], cy1[b], cx2[b], cy2[b], car[b]))
            bits |= (1ull << b);
    }
    mask[(size_t)i * 64 + w] = bits;
    if (w == (i >> 6)) diag[i] = bits;
    u64 anyb = __ballot(bits != 0ull);
    if ((tid & 63) == 0 && anyb) atomicOr(&supany[i >> 6], anyb);
}

// 512 threads: build valm from valid via ballots; preload suppressor rows + diag; wave 0 scans
__global__ __launch_bounds__(512) void k_scan_nms(const u64* __restrict__ mask,
                                                  const u64* __restrict__ diag,
                                                  const u64* __restrict__ supany,
                                                  const u32* __restrict__ valid,
                                                  float* __restrict__ out) {
    __shared__ u64 dlds[NWORD * 64];
    __shared__ u64 cache[RCACHE * 64];
    __shared__ u32 rowlist[RCACHE];
    __shared__ u32 nrows_s;
    __shared__ u64 vml[64];
    __shared__ u64 keep_s[64];
    int tid = threadIdx.x;
    int wave = tid >> 6, lane = tid & 63;

    for (int g = wave; g < 64; g += 8) {
        int t = g * 64 + lane;
        u32 v = (t < TOPK) ? valid[t] : 0u;
        u64 bm = __ballot(v != 0u);
        if (lane == 0) vml[g] = bm;
    }
    for (int t = tid; t < NWORD * 64; t += 512)
        dlds[t] = (t < TOPK) ? diag[t] : 0ull;

    int excl = 0;
    u64 sa = 0;
    if (wave == 0) {
        sa = supany[lane];
        int c = (int)__popcll(sa);
        int pfx = c;
        for (int off = 1; off < 64; off <<= 1) {
            int n = __shfl_up(pfx, off);
            if (lane >= off) pfx += n;
        }
        excl = pfx - c;
        int total = __shfl(pfx, 63);
        if (lane == 0) nrows_s = (u32)((total < RCACHE) ? total : RCACHE);
        int s = excl; u64 t = sa;
        while (t) {
            int b = (int)__builtin_ctzll(t); t &= t - 1;
            if (s < RCACHE) rowlist[s] = (u32)((lane << 6) | b);
            s++;
        }
    }
    __syncthreads();
    int R = (int)nrows_s;
    {
        const int TW = RCACHE * 64;
        for (int t0 = tid; t0 < TW; t0 += 512 * 8) {
            u64 v[8];
#pragma unroll
            for (int u = 0; u < 8; ++u) {
                int t = t0 + u * 512;
                int sl = t >> 6;
                int row = (t < TW && sl < R) ? (int)rowlist[sl] : 0;
                v[u] = (t < TW) ? mask[(size_t)row * 64 + (t & 63)] : 0ull;
            }
#pragma unroll
            for (int u = 0; u < 8; ++u) {
                int t = t0 + u * 512;
                if (t < TW) cache[t] = v[u];
            }
        }
    }
    __syncthreads();
    if (wave == 0) {
        u64 kw = vml[lane];
        u64 gm = __ballot((sa & kw) != 0ull);
        while (gm) {
            int g = (int)__builtin_ctzll(gm); gm &= gm - 1;
            u64 wg  = __shfl(kw, g);
            u64 sag = __shfl(sa, g);
            u64 supAlive = wg & sag;
            if (supAlive == 0ull) continue;
            int sbase = __shfl(excl, g);
            u64 dg = dlds[(g << 6) | lane];
            u64 am = wg, act = supAlive, keptSup = 0ull;
            while (act) {
                int s = (int)__builtin_ctzll(act);
                u64 sup = __shfl(dg, s);
                am &= ~sup;
                keptSup |= (1ull << s);
                act &= ~(1ull << s);
                act &= am;
            }
            u64 acc = 0, t = keptSup;
            while (t) {
                int s1b = (int)__builtin_ctzll(t); t &= t - 1;
                int sl1 = sbase + (int)__popcll(sag & ((1ull << s1b) - 1ull));
                if (t) {
                    int s2b = (int)__builtin_ctzll(t); t &= t - 1;
                    int sl2 = sbase + (int)__popcll(sag & ((1ull << s2b) - 1ull));
                    u64 ra = (sl1 < RCACHE) ? cache[(sl1 << 6) | lane]
                                            : mask[(size_t)((g << 6) | s1b) * 64 + lane];
                    u64 rb = (sl2 < RCACHE) ? cache[(sl2 << 6) | lane]
                                            : mask[(size_t)((g << 6) | s2b) * 64 + lane];
                    acc |= ra | rb;
                } else {
                    acc |= (sl1 < RCACHE) ? cache[(sl1 << 6) | lane]
                                          : mask[(size_t)((g << 6) | s1b) * 64 + lane];
                }
            }
            kw &= ~acc;
        }
        keep_s[lane] = kw;
    }
    __syncthreads();
    for (int t = tid; t < TOPK; t += 512)
        out[24000 + t] = ((keep_s[t >> 6] >> (t & 63)) & 1ull) ? 1.0f : 0.0f;
}

extern "C" void kernel_launch(void* const* d_in, const int* in_sizes, int n_in,
                              void* d_out, int out_size, void* d_ws, size_t ws_size,
                              hipStream_t stream) {
    const float* obj  = (const float*)d_in[0];
    const float* reg  = (const float*)d_in[1];
    const float* anch = (const float*)d_in[2];
    float* out = (float*)d_out;
    char* ws = (char*)d_ws;

    u32* meta = (u32*)(ws + WS_META);
    u64* supany = (u64*)(ws + WS_SUP);
    u64* ckeyp = (u64*)(ws + WS_CKEY);
    float* nx1 = (float*)(ws + WS_NX1);
    float* ny1 = (float*)(ws + WS_NY1);
    float* nx2 = (float*)(ws + WS_NX2);
    float* ny2 = (float*)(ws + WS_NY2);
    float* nar = (float*)(ws + WS_NAR);
    u32* valid = (u32*)(ws + WS_VAL);
    u64* mask  = (u64*)(ws + WS_MASK);
    u64* diag  = (u64*)(ws + WS_DIAG);
    u32* rankbuf = (u32*)(ws + WS_RANK);
    u64* coarse  = (u64*)(ws + WS_COARSE);

    hipLaunchKernelGGL(k_zero, dim3(1), dim3(256), 0, stream, (u32*)ws);
    hipLaunchKernelGGL(k_coarse, dim3(NANCH / 4608), dim3(256), 0, stream,
                       (const float4*)obj, coarse, meta);
    hipLaunchKernelGGL(k_select, dim3(1), dim3(1024), 0, stream, coarse, meta);
    hipLaunchKernelGGL(k_key, dim3(CAP/256), dim3(256), 0, stream, obj, meta, coarse, ckeyp);
    hipLaunchKernelGGL(k_rank, dim3(NSLICE, CAP/256), dim3(256), 0, stream, meta, ckeyp, rankbuf);
    hipLaunchKernelGGL(k_selgather, dim3(CAP/256), dim3(256), 0, stream,
                       meta, ckeyp, rankbuf, obj, reg, anch, out,
                       nx1, ny1, nx2, ny2, nar, valid);
    hipLaunchKernelGGL(k_mask, dim3((TOPK + 255) / 256, 64), dim3(256), 0, stream,
                       nx1, ny1, nx2, ny2, nar, mask, diag, supany);
    hipLaunchKernelGGL(k_scan_nms, dim3(1), dim3(512), 0, stream, mask, diag, supany, valid, out);
}